// Round 1
// baseline (3590.459 us; speedup 1.0000x reference)
//
#include <hip/hip_runtime.h>

#define LSEQ   100
#define TQ     1600      // B * LSEQ
#define DMODEL 512
#define NH     8
#define HD     64
#define VOCAB  32000
#define HIDDEN 2048

__device__ __forceinline__ float wredsum(float v) {
#pragma unroll
  for (int o = 32; o > 0; o >>= 1) v += __shfl_xor(v, o, 64);
  return v;
}
__device__ __forceinline__ float wredmax(float v) {
#pragma unroll
  for (int o = 32; o > 0; o >>= 1) v = fmaxf(v, __shfl_xor(v, o, 64));
  return v;
}

// out[row][d] = sw[tok[row]][d] + pe(row % LSEQ, d)
__global__ __launch_bounds__(256) void embed_kernel(const int* __restrict__ tok,
                                                    const float* __restrict__ sw,
                                                    float* __restrict__ out) {
  int idx = blockIdx.x * 256 + threadIdx.x;       // 0 .. TQ*DMODEL-1
  int row = idx >> 9, d = idx & 511;
  int l = row % LSEQ;
  int t = tok[row];
  // freq = 10000^(-(d/2)/512)
  float freq = expf(-(float)(d >> 1) * (9.210340371976184f / 512.0f));
  float ang = (float)l * freq;
  float pe = (d & 1) ? cosf(ang) : sinf(ang);
  out[idx] = sw[(size_t)t * DMODEL + d] + pe;
}

// C[M,N] = A[M,K] @ B + bias (+res) (+relu) (vscale: acc *= 512^-0.5 before bias)
// BT=false: B is [K][N] row-major.  BT=true: B is [N][K] row-major (i.e. C = A @ B^T).
// Requires M%64==0, N%64==0, K%16==0 (true for all our shapes).
template<bool BT, bool RELU, bool RES, bool VSCALE>
__global__ __launch_bounds__(256) void gemm_kernel(
    const float* __restrict__ A, const float* __restrict__ B,
    const float* __restrict__ bias, const float* __restrict__ Rm,
    float* __restrict__ C, int M, int N, int K)
{
  __shared__ float As[16][65];
  __shared__ float Bs[16][65];
  const int tid = threadIdx.x;
  const int m0 = blockIdx.y << 6, n0 = blockIdx.x << 6;
  const int ar = tid >> 2, ac = (tid & 3) << 2;   // A loader: row 0..63, col {0,4,8,12}
  const int ty = tid >> 4, tx = tid & 15;
  float acc[4][4] = {};
  for (int k0 = 0; k0 < K; k0 += 16) {
    __syncthreads();
    float4 av = *(const float4*)(A + (size_t)(m0 + ar) * K + k0 + ac);
    As[ac + 0][ar] = av.x; As[ac + 1][ar] = av.y;
    As[ac + 2][ar] = av.z; As[ac + 3][ar] = av.w;
    if (!BT) {
      const int br = tid >> 4, bc = (tid & 15) << 2;   // k-row 0..15, n-col {0..60}
      float4 bv = *(const float4*)(B + (size_t)(k0 + br) * N + n0 + bc);
      Bs[br][bc + 0] = bv.x; Bs[br][bc + 1] = bv.y;
      Bs[br][bc + 2] = bv.z; Bs[br][bc + 3] = bv.w;
    } else {
      const int bn = tid >> 2, bk = (tid & 3) << 2;    // n-row 0..63, k-col {0,4,8,12}
      float4 bv = *(const float4*)(B + (size_t)(n0 + bn) * K + k0 + bk);
      Bs[bk + 0][bn] = bv.x; Bs[bk + 1][bn] = bv.y;
      Bs[bk + 2][bn] = bv.z; Bs[bk + 3][bn] = bv.w;
    }
    __syncthreads();
#pragma unroll
    for (int kk = 0; kk < 16; ++kk) {
      float a[4], b[4];
#pragma unroll
      for (int i = 0; i < 4; ++i) a[i] = As[kk][ty * 4 + i];
#pragma unroll
      for (int j = 0; j < 4; ++j) b[j] = Bs[kk][tx * 4 + j];
#pragma unroll
      for (int i = 0; i < 4; ++i)
#pragma unroll
        for (int j = 0; j < 4; ++j) acc[i][j] = fmaf(a[i], b[j], acc[i][j]);
    }
  }
#pragma unroll
  for (int i = 0; i < 4; ++i) {
    int m = m0 + ty * 4 + i;
    float4 o;
    float* po = (float*)&o;
#pragma unroll
    for (int j = 0; j < 4; ++j) {
      int n = n0 + tx * 4 + j;
      float v = acc[i][j];
      if (VSCALE) v *= 0.044194173824159216f;  // 512^-0.5
      v += bias[n];
      if (RES) v += Rm[(size_t)m * N + n];
      if (RELU) v = fmaxf(v, 0.0f);
      po[j] = v;
    }
    *(float4*)(C + (size_t)m * N + n0 + tx * 4) = o;
  }
}

// In-place LayerNorm over rows of 512. One wave per row.
__global__ __launch_bounds__(64) void ln_kernel(float* __restrict__ X,
                                                const float* __restrict__ g,
                                                const float* __restrict__ b) {
  int row = blockIdx.x, lane = threadIdx.x;
  float* p = X + (size_t)row * DMODEL + lane * 8;
  float4 v0 = *(float4*)p, v1 = *(float4*)(p + 4);
  float x[8] = {v0.x, v0.y, v0.z, v0.w, v1.x, v1.y, v1.z, v1.w};
  float s = 0.f;
#pragma unroll
  for (int j = 0; j < 8; ++j) s += x[j];
  s = wredsum(s);
  float mean = s * (1.0f / 512.0f);
  float d2 = 0.f;
#pragma unroll
  for (int j = 0; j < 8; ++j) { float d = x[j] - mean; d2 += d * d; }
  d2 = wredsum(d2);
  float r = rsqrtf(d2 * (1.0f / 512.0f) + 1e-5f);
  const float* gg = g + lane * 8;
  const float* bb = b + lane * 8;
  float y[8];
#pragma unroll
  for (int j = 0; j < 8; ++j) y[j] = (x[j] - mean) * r * gg[j] + bb[j];
  *(float4*)p       = make_float4(y[0], y[1], y[2], y[3]);
  *(float4*)(p + 4) = make_float4(y[4], y[5], y[6], y[7]);
}

// Attention core for one (b,h) per block. Q,K,V are [TQ][DMODEL] with head h at
// feature offset h*HD (head-major). Output written rearranged: O[t][d*NH + h].
// Mask: key k valid iff tok[b*LSEQ+k] != 0 (and k <= l if causal). Scores are
// scaled by 1/8 then masked to -1e9 (matching the reference order).
__global__ __launch_bounds__(256) void attn_kernel(
    const float* __restrict__ Q, const float* __restrict__ K,
    const float* __restrict__ V, const int* __restrict__ tok,
    float* __restrict__ O, int causal)
{
  __shared__ float Ks[LSEQ * 65];
  __shared__ float Vs[LSEQ * 64];
  __shared__ float Ps[4][LSEQ];
  int b = blockIdx.x >> 3, h = blockIdx.x & 7;
  int tid = threadIdx.x;
  for (int i = tid; i < LSEQ * 64; i += 256) {
    int k = i >> 6, d = i & 63;
    size_t src = (size_t)(b * LSEQ + k) * DMODEL + h * HD + d;
    Ks[k * 65 + d] = K[src];
    Vs[i] = V[src];
  }
  __syncthreads();
  int wave = tid >> 6, lane = tid & 63;
  int k2 = lane + 64;
  int k2c = (k2 < LSEQ) ? k2 : (LSEQ - 1);
  bool pad1 = (tok[b * LSEQ + lane] != 0);
  bool pad2 = (k2 < LSEQ) ? (tok[b * LSEQ + k2] != 0) : false;
  const float* qbase = Q + (size_t)b * LSEQ * DMODEL + h * HD;
  for (int l = wave; l < LSEQ; l += 4) {
    const float* q = qbase + (size_t)l * DMODEL;
    float s1 = 0.f, s2 = 0.f;
#pragma unroll 8
    for (int d = 0; d < 64; ++d) {
      float qd = q[d];
      s1 = fmaf(qd, Ks[lane * 65 + d], s1);
      s2 = fmaf(qd, Ks[k2c * 65 + d], s2);
    }
    bool ok1 = pad1 && (!causal || lane <= l);
    bool ok2 = (k2 < LSEQ) && pad2 && (!causal || k2 <= l);
    s1 = ok1 ? s1 * 0.125f : -1e9f;
    s2 = ok2 ? s2 * 0.125f : ((k2 < LSEQ) ? -1e9f : -1e30f);
    float m = wredmax(fmaxf(s1, s2));
    float e1 = __expf(s1 - m);
    float e2 = __expf(s2 - m);
    float sum = wredsum(e1 + e2);
    float inv = 1.0f / sum;
    Ps[wave][lane] = e1 * inv;
    if (k2 < LSEQ) Ps[wave][k2] = e2 * inv;
    float acc = 0.f;
#pragma unroll 4
    for (int k = 0; k < LSEQ; ++k) acc = fmaf(Ps[wave][k], Vs[k * 64 + lane], acc);
    O[(size_t)(b * LSEQ + l) * DMODEL + lane * NH + h] = acc;
  }
}

// In-place row softmax over VOCAB on d_out.
__global__ __launch_bounds__(256) void vsoftmax_kernel(float* __restrict__ P) {
  __shared__ float red[4];
  int row = blockIdx.x, tid = threadIdx.x;
  float* p = P + (size_t)row * VOCAB;
  float m = -1e30f;
  for (int i = tid; i < VOCAB; i += 256) m = fmaxf(m, p[i]);
  m = wredmax(m);
  if ((tid & 63) == 0) red[tid >> 6] = m;
  __syncthreads();
  m = fmaxf(fmaxf(red[0], red[1]), fmaxf(red[2], red[3]));
  float s = 0.f;
  for (int i = tid; i < VOCAB; i += 256) s += __expf(p[i] - m);
  s = wredsum(s);
  __syncthreads();
  if ((tid & 63) == 0) red[tid >> 6] = s;
  __syncthreads();
  s = red[0] + red[1] + red[2] + red[3];
  float inv = 1.0f / s;
  for (int i = tid; i < VOCAB; i += 256) p[i] = __expf(p[i] - m) * inv;
}

extern "C" void kernel_launch(void* const* d_in, const int* in_sizes, int n_in,
                              void* d_out, int out_size, void* d_ws, size_t ws_size,
                              hipStream_t stream) {
  (void)in_sizes; (void)n_in; (void)out_size; (void)ws_size;
  const int* inputs  = (const int*)d_in[0];
  const int* outputs = (const int*)d_in[1];
  const float* sw  = (const float*)d_in[2];
  const float* fcb = (const float*)d_in[3];
  // per-stack weights: 0 wq 1 bq 2 wk 3 bk 4 wv 5 bv 6 wo 7 bo 8 g1 9 b1
  //                    10 f1w 11 f1b 12 f2w 13 f2b 14 g2 15 b2
  const float* E[16];
  const float* Dw[16];
  for (int i = 0; i < 16; ++i) E[i]  = (const float*)d_in[4 + i];
  for (int i = 0; i < 16; ++i) Dw[i] = (const float*)d_in[20 + i];

  // Persistent activations live in ws (small); transient buffers are carved out
  // of d_out — they are dead before the final vocab GEMM overwrites all of d_out.
  float* ws   = (float*)d_ws;
  float* bufE = ws;                 // TQ*DMODEL
  float* bufD = bufE + TQ * DMODEL; // TQ*DMODEL
  float* sc   = (float*)d_out;
  float* bq = sc;
  float* bk = bq + TQ * DMODEL;
  float* bv = bk + TQ * DMODEL;
  float* ba = bv + TQ * DMODEL;
  float* bh = ba + TQ * DMODEL;     // TQ*HIDDEN
  float* out = (float*)d_out;

  const dim3 G512(DMODEL / 64, TQ / 64);   // (8,25)
  const dim3 GHID(HIDDEN / 64, TQ / 64);   // (32,25)
  const dim3 GVOC(VOCAB / 64, TQ / 64);    // (500,25)

  embed_kernel<<<TQ * DMODEL / 256, 256, 0, stream>>>(inputs, sw, bufE);
  embed_kernel<<<TQ * DMODEL / 256, 256, 0, stream>>>(outputs, sw, bufD);

  // ---- encoder: 2 iterations, shared weights ----
  for (int it = 0; it < 2; ++it) {
    gemm_kernel<false,false,false,false><<<G512,256,0,stream>>>(bufE, E[0], E[1], nullptr, bq, TQ, DMODEL, DMODEL);
    gemm_kernel<false,false,false,false><<<G512,256,0,stream>>>(bufE, E[2], E[3], nullptr, bk, TQ, DMODEL, DMODEL);
    gemm_kernel<false,false,false,false><<<G512,256,0,stream>>>(bufE, E[4], E[5], nullptr, bv, TQ, DMODEL, DMODEL);
    attn_kernel<<<128,256,0,stream>>>(bq, bk, bv, inputs, ba, 0);
    gemm_kernel<false,false,true,false><<<G512,256,0,stream>>>(ba, E[6], E[7], bufE, bufE, TQ, DMODEL, DMODEL);
    ln_kernel<<<TQ,64,0,stream>>>(bufE, E[8], E[9]);
    gemm_kernel<false,true,false,false><<<GHID,256,0,stream>>>(bufE, E[10], E[11], nullptr, bh, TQ, HIDDEN, DMODEL);
    gemm_kernel<false,false,true,false><<<G512,256,0,stream>>>(bh, E[12], E[13], bufE, bufE, TQ, DMODEL, HIDDEN);
    ln_kernel<<<TQ,64,0,stream>>>(bufE, E[14], E[15]);
  }

  // ---- decoder: 2 iterations ----
  for (int it = 0; it < 2; ++it) {
    // self-attention (causal + key-padding on outputs)
    gemm_kernel<false,false,false,false><<<G512,256,0,stream>>>(bufD, Dw[0], Dw[1], nullptr, bq, TQ, DMODEL, DMODEL);
    gemm_kernel<false,false,false,false><<<G512,256,0,stream>>>(bufD, Dw[2], Dw[3], nullptr, bk, TQ, DMODEL, DMODEL);
    gemm_kernel<false,false,false,false><<<G512,256,0,stream>>>(bufD, Dw[4], Dw[5], nullptr, bv, TQ, DMODEL, DMODEL);
    attn_kernel<<<128,256,0,stream>>>(bq, bk, bv, outputs, ba, 1);
    gemm_kernel<false,false,true,false><<<G512,256,0,stream>>>(ba, Dw[6], Dw[7], bufD, bufD, TQ, DMODEL, DMODEL);
    ln_kernel<<<TQ,64,0,stream>>>(bufD, Dw[8], Dw[9]);
    // cross-attention (key-padding on inputs, K/V from encoder output)
    gemm_kernel<false,false,false,false><<<G512,256,0,stream>>>(bufD, Dw[0], Dw[1], nullptr, bq, TQ, DMODEL, DMODEL);
    gemm_kernel<false,false,false,false><<<G512,256,0,stream>>>(bufE, Dw[2], Dw[3], nullptr, bk, TQ, DMODEL, DMODEL);
    gemm_kernel<false,false,false,false><<<G512,256,0,stream>>>(bufE, Dw[4], Dw[5], nullptr, bv, TQ, DMODEL, DMODEL);
    attn_kernel<<<128,256,0,stream>>>(bq, bk, bv, inputs, ba, 0);
    gemm_kernel<false,false,true,false><<<G512,256,0,stream>>>(ba, Dw[6], Dw[7], bufD, bufD, TQ, DMODEL, DMODEL);
    ln_kernel<<<TQ,64,0,stream>>>(bufD, Dw[8], Dw[9]);
    // feed-forward
    gemm_kernel<false,true,false,false><<<GHID,256,0,stream>>>(bufD, Dw[10], Dw[11], nullptr, bh, TQ, HIDDEN, DMODEL);
    gemm_kernel<false,false,true,false><<<G512,256,0,stream>>>(bh, Dw[12], Dw[13], bufD, bufD, TQ, DMODEL, HIDDEN);
    ln_kernel<<<TQ,64,0,stream>>>(bufD, Dw[14], Dw[15]);
  }

  // ---- final: logits = (dec * 512^-0.5) @ sw^T + fc_b ; softmax over vocab ----
  gemm_kernel<true,false,false,true><<<GVOC,256,0,stream>>>(bufD, sw, fcb, nullptr, out, TQ, VOCAB, DMODEL);
  vsoftmax_kernel<<<TQ,256,0,stream>>>(out);
}

// Round 2
// 983.680 us; speedup vs baseline: 3.6500x; 3.6500x over previous
//
#include <hip/hip_runtime.h>

#define TQ     1600
#define MP     1664        // padded rows (26*64)
#define DM     512
#define NHD    8
#define HD     64
#define VOCAB  32000
#define HID    2048
#define LSEQ   100
#define SCALEV 0.044194173824159216f   // 512^-0.5

typedef unsigned short u16;
typedef __attribute__((ext_vector_type(8))) short bf16x8;
typedef __attribute__((ext_vector_type(4))) float f32x4;

__device__ __forceinline__ u16 f2b(float x) {
  union { float f; unsigned u; } c; c.f = x;
  unsigned r = (c.u + 0x7FFFu + ((c.u >> 16) & 1u)) >> 16;
  return (u16)r;
}
__device__ __forceinline__ float b2f(u16 b) {
  union { unsigned u; float f; } c; c.u = ((unsigned)b) << 16; return c.f;
}
__device__ __forceinline__ unsigned pk2(float lo, float hi) {
  return (unsigned)f2b(lo) | ((unsigned)f2b(hi) << 16);
}
__device__ __forceinline__ float wredsum(float v) {
#pragma unroll
  for (int o = 32; o > 0; o >>= 1) v += __shfl_xor(v, o, 64);
  return v;
}
__device__ __forceinline__ float wredmax(float v) {
#pragma unroll
  for (int o = 32; o > 0; o >>= 1) v = fmaxf(v, __shfl_xor(v, o, 64));
  return v;
}

// ---------------- weight convert+transpose: src f32 [K][N] -> dst bf16 [N][K]
__global__ __launch_bounds__(256) void cvtT_kernel(const float* __restrict__ src,
                                                   u16* __restrict__ dst, int K, int N) {
  __shared__ float t[64][65];
  int k0 = blockIdx.x * 64, n0 = blockIdx.y * 64;
  int tid = threadIdx.x;
  int r = tid >> 4, c = (tid & 15) * 4;
#pragma unroll
  for (int i = 0; i < 4; ++i) {
    float4 v = *(const float4*)(src + (size_t)(k0 + r + i * 16) * N + n0 + c);
    t[r + i * 16][c + 0] = v.x; t[r + i * 16][c + 1] = v.y;
    t[r + i * 16][c + 2] = v.z; t[r + i * 16][c + 3] = v.w;
  }
  __syncthreads();
#pragma unroll
  for (int i = 0; i < 4; ++i) {
    int n = r + i * 16;
    ushort4 o;
    o.x = f2b(t[c + 0][n]); o.y = f2b(t[c + 1][n]);
    o.z = f2b(t[c + 2][n]); o.w = f2b(t[c + 3][n]);
    *(ushort4*)(dst + (size_t)(n0 + n) * K + k0 + c) = o;
  }
}

__global__ void biascat_kernel(const float* a, const float* b, const float* c,
                               float* dst) {
  int t = blockIdx.x * 256 + threadIdx.x;
  if (t < 512) { dst[t] = a[t]; dst[512 + t] = b[t]; dst[1024 + t] = c[t]; }
}

// ---------------- embedding + positional encoding -> bf16 (pad rows zeroed)
__global__ __launch_bounds__(256) void embed_kernel(const int* __restrict__ tok,
                                                    const float* __restrict__ sw,
                                                    u16* __restrict__ out) {
  int idx = blockIdx.x * 256 + threadIdx.x;      // 0 .. MP*DM-1
  int row = idx >> 9, d = idx & 511;
  float v = 0.f;
  if (row < TQ) {
    int l = row % LSEQ;
    int t = tok[row];
    float freq = expf(-(float)(d >> 1) * (9.210340371976184f / 512.0f));
    float ang = (float)l * freq;
    float pe = (d & 1) ? cosf(ang) : sinf(ang);
    v = sw[(size_t)t * DM + d] + pe;
  }
  out[idx] = f2b(v);
}

// ---------------- generic bf16 MFMA GEMM, 64x64 tile, K%32==0
// A bf16 [MP][K] (lda=K); BT bf16 [N][K] (ldb=K); bias f32 [N];
// res bf16 [MP][ldc] (read at +col), C bf16 [MP][ldc] written at cols [0,N).
template<bool RELU, bool RES>
__global__ __launch_bounds__(256) void bgemm_kernel(
    const u16* __restrict__ A, const u16* __restrict__ BT,
    const float* __restrict__ bias, const u16* __restrict__ res,
    u16* __restrict__ C, int K, int ldc)
{
  __shared__ u16 As[64 * 32];
  __shared__ u16 Bs[64 * 32];
  const int tid = threadIdx.x;
  const int m0 = blockIdx.y << 6, n0 = blockIdx.x << 6;
  const int w = tid >> 6, lane = tid & 63;
  const int srow = tid >> 2, sc = tid & 3;
  const int sslot = sc ^ ((srow >> 1) & 3);
  const u16* ag = A + (size_t)(m0 + srow) * K + sc * 8;
  const u16* bg = BT + (size_t)(n0 + srow) * K + sc * 8;
  const int arow = w * 16 + (lane & 15);
  const int aslot = (lane >> 4) ^ ((arow >> 1) & 3);
  f32x4 acc[4];
#pragma unroll
  for (int t = 0; t < 4; ++t) acc[t] = (f32x4){0.f, 0.f, 0.f, 0.f};

  for (int k0 = 0; k0 < K; k0 += 32) {
    __syncthreads();
    uint4 av = *(const uint4*)(ag + k0);
    uint4 bv = *(const uint4*)(bg + k0);
    *(uint4*)&As[srow * 32 + sslot * 8] = av;
    *(uint4*)&Bs[srow * 32 + sslot * 8] = bv;
    __syncthreads();
    bf16x8 af = *(bf16x8*)&As[arow * 32 + aslot * 8];
#pragma unroll
    for (int t = 0; t < 4; ++t) {
      int brow = t * 16 + (lane & 15);
      int bslot = (lane >> 4) ^ ((brow >> 1) & 3);
      bf16x8 bf = *(bf16x8*)&Bs[brow * 32 + bslot * 8];
      acc[t] = __builtin_amdgcn_mfma_f32_16x16x32_bf16(af, bf, acc[t], 0, 0, 0);
    }
  }
  const int r0 = (lane >> 4) * 4;
#pragma unroll
  for (int t = 0; t < 4; ++t) {
    int col = n0 + t * 16 + (lane & 15);
    float bsv = bias[col];
#pragma unroll
    for (int r = 0; r < 4; ++r) {
      int row = m0 + w * 16 + r0 + r;
      float v = acc[t][r] + bsv;
      if (RES) v += b2f(res[(size_t)row * ldc + col]);
      if (RELU) v = fmaxf(v, 0.f);
      C[(size_t)row * ldc + col] = f2b(v);
    }
  }
}

// ---------------- LayerNorm in-place on bf16 rows of 512 (one wave/row)
__global__ __launch_bounds__(64) void ln_kernel(u16* __restrict__ X,
                                                const float* __restrict__ g,
                                                const float* __restrict__ b) {
  int row = blockIdx.x, lane = threadIdx.x;
  u16* p = X + (size_t)row * DM + lane * 8;
  uint4 u = *(uint4*)p;
  unsigned uu[4] = {u.x, u.y, u.z, u.w};
  float x[8];
#pragma unroll
  for (int e = 0; e < 4; ++e) {
    x[e * 2]     = b2f((u16)(uu[e] & 0xffff));
    x[e * 2 + 1] = b2f((u16)(uu[e] >> 16));
  }
  float s = 0.f;
#pragma unroll
  for (int j = 0; j < 8; ++j) s += x[j];
  s = wredsum(s);
  float mean = s * (1.0f / 512.0f);
  float d2 = 0.f;
#pragma unroll
  for (int j = 0; j < 8; ++j) { float d = x[j] - mean; d2 += d * d; }
  d2 = wredsum(d2);
  float r = rsqrtf(d2 * (1.0f / 512.0f) + 1e-5f);
  const float* gg = g + lane * 8;
  const float* bb = b + lane * 8;
  float y[8];
#pragma unroll
  for (int j = 0; j < 8; ++j) y[j] = (x[j] - mean) * r * gg[j] + bb[j];
  uint4 o;
  o.x = pk2(y[0], y[1]); o.y = pk2(y[2], y[3]);
  o.z = pk2(y[4], y[5]); o.w = pk2(y[6], y[7]);
  *(uint4*)p = o;
}

// ---------------- attention: one (b,h) per block; QKV bf16 [MP][1536]
// q at col h*64, k at 512+h*64, v at 1024+h*64. O bf16 [MP][512] at col d*8+h.
__global__ __launch_bounds__(256) void attn_kernel(
    const u16* __restrict__ QKV, const int* __restrict__ tok,
    u16* __restrict__ O, int causal)
{
  __shared__ float Ks[LSEQ * 65];
  __shared__ float Vs[LSEQ * 64];
  __shared__ float Ps[4][LSEQ];
  int b = blockIdx.x >> 3, h = blockIdx.x & 7;
  int tid = threadIdx.x;
  for (int i = tid; i < LSEQ * 64; i += 256) {
    int k = i >> 6, d = i & 63;
    size_t row = (size_t)(b * LSEQ + k) * 1536;
    Ks[k * 65 + d] = b2f(QKV[row + 512 + h * 64 + d]);
    Vs[i]          = b2f(QKV[row + 1024 + h * 64 + d]);
  }
  __syncthreads();
  int wave = tid >> 6, lane = tid & 63;
  int k2 = lane + 64;
  int k2c = (k2 < LSEQ) ? k2 : (LSEQ - 1);
  bool pad1 = (tok[b * LSEQ + lane] != 0);
  bool pad2 = (k2 < LSEQ) ? (tok[b * LSEQ + k2] != 0) : false;
  for (int l = wave; l < LSEQ; l += 4) {
    const u16* q = QKV + (size_t)(b * LSEQ + l) * 1536 + h * 64;
    float s1 = 0.f, s2 = 0.f;
#pragma unroll
    for (int jj = 0; jj < 8; ++jj) {
      uint4 u = *(const uint4*)(q + jj * 8);
      unsigned uu[4] = {u.x, u.y, u.z, u.w};
#pragma unroll
      for (int e = 0; e < 4; ++e) {
        float f0 = b2f((u16)(uu[e] & 0xffff));
        float f1 = b2f((u16)(uu[e] >> 16));
        int d = jj * 8 + e * 2;
        s1 = fmaf(f0, Ks[lane * 65 + d], s1);
        s1 = fmaf(f1, Ks[lane * 65 + d + 1], s1);
        s2 = fmaf(f0, Ks[k2c * 65 + d], s2);
        s2 = fmaf(f1, Ks[k2c * 65 + d + 1], s2);
      }
    }
    bool ok1 = pad1 && (!causal || lane <= l);
    bool ok2 = (k2 < LSEQ) && pad2 && (!causal || k2 <= l);
    s1 = ok1 ? s1 * 0.125f : -1e9f;
    s2 = ok2 ? s2 * 0.125f : ((k2 < LSEQ) ? -1e9f : -1e30f);
    float m = wredmax(fmaxf(s1, s2));
    float e1 = __expf(s1 - m);
    float e2 = (k2 < LSEQ) ? __expf(s2 - m) : 0.f;
    float sum = wredsum(e1 + e2);
    float inv = 1.0f / sum;
    Ps[wave][lane] = e1 * inv;
    if (k2 < LSEQ) Ps[wave][k2] = e2 * inv;
    float acc = 0.f;
#pragma unroll 4
    for (int k = 0; k < LSEQ; ++k) acc = fmaf(Ps[wave][k], Vs[k * 64 + lane], acc);
    O[(size_t)(b * LSEQ + l) * DM + lane * 8 + h] = f2b(acc);
  }
}

// ---------------- vocab GEMM: out[1600][32000] f32 = (A bf16 [MP][512] * s) @ sw^T + fcb
// One block per 64-column stripe; sw stripe resident in LDS (fetched once);
// A-frags read directly from global (L2-resident).
__global__ __launch_bounds__(256) void vgemm_kernel(
    const u16* __restrict__ A, const float* __restrict__ sw,
    const float* __restrict__ fcb, float* __restrict__ out)
{
  __shared__ u16 Bs[64 * 512];   // 64 KB
  const int tid = threadIdx.x;
  const int n0 = blockIdx.x << 6;
  // stage B stripe: rows n0..n0+63 of sw (f32 -> bf16), swizzled
  for (int i = tid; i < 4096; i += 256) {
    int row = i >> 6, c = i & 63;
    int ks = c >> 2, cc = c & 3;
    int slot = ks * 4 + (cc ^ ((row >> 1) & 3));
    const float* s = sw + (size_t)(n0 + row) * DM + c * 8;
    float4 f0 = *(const float4*)s;
    float4 f1 = *(const float4*)(s + 4);
    uint4 o;
    o.x = pk2(f0.x, f0.y); o.y = pk2(f0.z, f0.w);
    o.z = pk2(f1.x, f1.y); o.w = pk2(f1.z, f1.w);
    *(uint4*)&Bs[row * 512 + slot * 8] = o;
  }
  __syncthreads();
  const int w = tid >> 6, lane = tid & 63;
  const u16* pA = A + (size_t)(w * 16 + (lane & 15)) * DM + (lane >> 4) * 8;
  float fb[4];
#pragma unroll
  for (int t = 0; t < 4; ++t) fb[t] = fcb[n0 + t * 16 + (lane & 15)];
  const int r0 = (lane >> 4) * 4;
  for (int mt = 0; mt < 25; ++mt) {
    f32x4 acc[4];
#pragma unroll
    for (int t = 0; t < 4; ++t) acc[t] = (f32x4){0.f, 0.f, 0.f, 0.f};
    size_t moff = (size_t)mt * 64 * DM;
#pragma unroll 4
    for (int ks = 0; ks < 16; ++ks) {
      uint4 ua = *(const uint4*)(pA + moff + ks * 32);
      union { uint4 u; bf16x8 b; } ca; ca.u = ua;
#pragma unroll
      for (int t = 0; t < 4; ++t) {
        int brow = t * 16 + (lane & 15);
        int bslot = ks * 4 + ((lane >> 4) ^ ((brow >> 1) & 3));
        bf16x8 bf = *(bf16x8*)&Bs[brow * 512 + bslot * 8];
        acc[t] = __builtin_amdgcn_mfma_f32_16x16x32_bf16(ca.b, bf, acc[t], 0, 0, 0);
      }
    }
#pragma unroll
    for (int t = 0; t < 4; ++t) {
      int col = n0 + t * 16 + (lane & 15);
#pragma unroll
      for (int r = 0; r < 4; ++r) {
        int row = mt * 64 + w * 16 + r0 + r;
        out[(size_t)row * VOCAB + col] = acc[t][r] * SCALEV + fb[t];
      }
    }
  }
}

// ---------------- in-place vocab softmax, 2-pass online (one block/row)
__global__ __launch_bounds__(256) void vsoftmax_kernel(float* __restrict__ P) {
  __shared__ float sm[4], ss[4];
  int row = blockIdx.x, tid = threadIdx.x;
  float* p = P + (size_t)row * VOCAB;
  float m = -1e30f, s = 0.f;
  for (int i = tid; i < VOCAB; i += 256) {
    float x = p[i];
    if (x > m) { s *= __expf(m - x); m = x; }
    s += __expf(x - m);
  }
#pragma unroll
  for (int o = 32; o > 0; o >>= 1) {
    float m2 = __shfl_xor(m, o, 64);
    float s2 = __shfl_xor(s, o, 64);
    float mn = fmaxf(m, m2);
    s = s * __expf(m - mn) + s2 * __expf(m2 - mn);
    m = mn;
  }
  if ((tid & 63) == 0) { sm[tid >> 6] = m; ss[tid >> 6] = s; }
  __syncthreads();
  float M = sm[0], S = ss[0];
#pragma unroll
  for (int k = 1; k < 4; ++k) {
    float mn = fmaxf(M, sm[k]);
    S = S * __expf(M - mn) + ss[k] * __expf(sm[k] - mn);
    M = mn;
  }
  float inv = 1.0f / S;
  for (int i = tid; i < VOCAB; i += 256) p[i] = __expf(p[i] - M) * inv;
}

extern "C" void kernel_launch(void* const* d_in, const int* in_sizes, int n_in,
                              void* d_out, int out_size, void* d_ws, size_t ws_size,
                              hipStream_t stream) {
  (void)in_sizes; (void)n_in; (void)out_size; (void)ws_size;
  const int* inputs  = (const int*)d_in[0];
  const int* outputs = (const int*)d_in[1];
  const float* sw  = (const float*)d_in[2];
  const float* fcb = (const float*)d_in[3];
  const float* E[16];
  const float* Dd[16];
  for (int i = 0; i < 16; ++i) E[i]  = (const float*)d_in[4 + i];
  for (int i = 0; i < 16; ++i) Dd[i] = (const float*)d_in[20 + i];

  // ws: persistent activations (bf16, padded MP rows)
  u16* bufE = (u16*)d_ws;            // MP*DM
  u16* bufD = bufE + (size_t)MP * DM;

  // transient carve from d_out (all dead before vgemm writes out)
  char* base = (char*)d_out;
  size_t off = 0;
  auto carve = [&](size_t bytes) { void* p = base + off; off += (bytes + 255) & ~(size_t)255; return p; };
  u16* bqkvE = (u16*)carve((size_t)MP * 1536 * 2);
  u16* bqkvD = (u16*)carve((size_t)MP * 1536 * 2);
  u16* ba    = (u16*)carve((size_t)MP * DM * 2);
  u16* bh    = (u16*)carve((size_t)MP * HID * 2);
  u16* wqkvE = (u16*)carve((size_t)1536 * 512 * 2);
  u16* woE   = (u16*)carve((size_t)512 * 512 * 2);
  u16* f1E   = (u16*)carve((size_t)2048 * 512 * 2);
  u16* f2E   = (u16*)carve((size_t)512 * 2048 * 2);
  u16* wqkvD = (u16*)carve((size_t)1536 * 512 * 2);
  u16* woD   = (u16*)carve((size_t)512 * 512 * 2);
  u16* f1D   = (u16*)carve((size_t)2048 * 512 * 2);
  u16* f2D   = (u16*)carve((size_t)512 * 2048 * 2);
  float* qbE = (float*)carve(1536 * 4);
  float* qbD = (float*)carve(1536 * 4);
  float* out = (float*)d_out;

  const dim3 T88(8, 8), T8_32(8, 32), T32_8(32, 8);
  // ---- weight conversion (f32 [K][N] -> bf16 [N][K]) ----
  cvtT_kernel<<<T88, 256, 0, stream>>>(E[0], wqkvE, 512, 512);
  cvtT_kernel<<<T88, 256, 0, stream>>>(E[2], wqkvE + 512 * 512, 512, 512);
  cvtT_kernel<<<T88, 256, 0, stream>>>(E[4], wqkvE + 1024 * 512, 512, 512);
  cvtT_kernel<<<T88, 256, 0, stream>>>(E[6], woE, 512, 512);
  cvtT_kernel<<<T8_32, 256, 0, stream>>>(E[10], f1E, 512, 2048);
  cvtT_kernel<<<T32_8, 256, 0, stream>>>(E[12], f2E, 2048, 512);
  cvtT_kernel<<<T88, 256, 0, stream>>>(Dd[0], wqkvD, 512, 512);
  cvtT_kernel<<<T88, 256, 0, stream>>>(Dd[2], wqkvD + 512 * 512, 512, 512);
  cvtT_kernel<<<T88, 256, 0, stream>>>(Dd[4], wqkvD + 1024 * 512, 512, 512);
  cvtT_kernel<<<T88, 256, 0, stream>>>(Dd[6], woD, 512, 512);
  cvtT_kernel<<<T8_32, 256, 0, stream>>>(Dd[10], f1D, 512, 2048);
  cvtT_kernel<<<T32_8, 256, 0, stream>>>(Dd[12], f2D, 2048, 512);
  biascat_kernel<<<2, 256, 0, stream>>>(E[1], E[3], E[5], qbE);
  biascat_kernel<<<2, 256, 0, stream>>>(Dd[1], Dd[3], Dd[5], qbD);

  embed_kernel<<<MP * DM / 256, 256, 0, stream>>>(inputs, sw, bufE);
  embed_kernel<<<MP * DM / 256, 256, 0, stream>>>(outputs, sw, bufD);

  const dim3 Gqkv(24, 26), G512(8, 26), Gkv(16, 26), Ghid(32, 26);

  // ---- encoder ----
  for (int it = 0; it < 2; ++it) {
    bgemm_kernel<false,false><<<Gqkv,256,0,stream>>>(bufE, wqkvE, qbE, nullptr, bqkvE, 512, 1536);
    attn_kernel<<<128,256,0,stream>>>(bqkvE, inputs, ba, 0);
    bgemm_kernel<false,true><<<G512,256,0,stream>>>(ba, woE, E[7], bufE, bufE, 512, 512);
    ln_kernel<<<TQ,64,0,stream>>>(bufE, E[8], E[9]);
    bgemm_kernel<true,false><<<Ghid,256,0,stream>>>(bufE, f1E, E[11], nullptr, bh, 512, 2048);
    bgemm_kernel<false,true><<<G512,256,0,stream>>>(bh, f2E, E[13], bufE, bufE, 2048, 512);
    ln_kernel<<<TQ,64,0,stream>>>(bufE, E[14], E[15]);
  }
  // ---- decoder ----
  for (int it = 0; it < 2; ++it) {
    bgemm_kernel<false,false><<<Gqkv,256,0,stream>>>(bufD, wqkvD, qbD, nullptr, bqkvD, 512, 1536);
    attn_kernel<<<128,256,0,stream>>>(bqkvD, outputs, ba, 1);
    bgemm_kernel<false,true><<<G512,256,0,stream>>>(ba, woD, Dd[7], bufD, bufD, 512, 512);
    ln_kernel<<<TQ,64,0,stream>>>(bufD, Dd[8], Dd[9]);
    // cross-attn: Q from bufD (cols 0..511), K/V from bufE (cols 512..1535)
    bgemm_kernel<false,false><<<G512,256,0,stream>>>(bufD, wqkvD, qbD, nullptr, bqkvD, 512, 1536);
    bgemm_kernel<false,false><<<Gkv,256,0,stream>>>(bufE, wqkvD + 512 * 512, qbD + 512, nullptr, bqkvD + 512, 512, 1536);
    attn_kernel<<<128,256,0,stream>>>(bqkvD, inputs, ba, 0);
    bgemm_kernel<false,true><<<G512,256,0,stream>>>(ba, woD, Dd[7], bufD, bufD, 512, 512);
    ln_kernel<<<TQ,64,0,stream>>>(bufD, Dd[8], Dd[9]);
    bgemm_kernel<true,false><<<Ghid,256,0,stream>>>(bufD, f1D, Dd[11], nullptr, bh, 512, 2048);
    bgemm_kernel<false,true><<<G512,256,0,stream>>>(bh, f2D, Dd[13], bufD, bufD, 2048, 512);
    ln_kernel<<<TQ,64,0,stream>>>(bufD, Dd[14], Dd[15]);
  }

  vgemm_kernel<<<VOCAB / 64, 256, 0, stream>>>(bufD, sw, fcb, out);
  vsoftmax_kernel<<<TQ, 256, 0, stream>>>(out);
}

// Round 3
// 587.834 us; speedup vs baseline: 6.1079x; 1.6734x over previous
//
#include <hip/hip_runtime.h>

#define TQ     1600
#define MP     1664        // padded rows (26*64)
#define DM     512
#define NHD    8
#define HD     64
#define VOCAB  32000
#define HID    2048
#define LSEQ   100
#define NSTRIPE 500        // vocab stripes of 64
#define SCALEV 0.044194173824159216f   // 512^-0.5

typedef unsigned short u16;
typedef unsigned int u32;
typedef __attribute__((ext_vector_type(8))) short bf16x8;
typedef __attribute__((ext_vector_type(4))) float f32x4;

__device__ __forceinline__ u16 f2b(float x) {
  union { float f; unsigned u; } c; c.f = x;
  unsigned r = (c.u + 0x7FFFu + ((c.u >> 16) & 1u)) >> 16;
  return (u16)r;
}
__device__ __forceinline__ float b2f(u16 b) {
  union { unsigned u; float f; } c; c.u = ((unsigned)b) << 16; return c.f;
}
__device__ __forceinline__ unsigned pk2(float lo, float hi) {
  return (unsigned)f2b(lo) | ((unsigned)f2b(hi) << 16);
}
__device__ __forceinline__ float wredsum(float v) {
#pragma unroll
  for (int o = 32; o > 0; o >>= 1) v += __shfl_xor(v, o, 64);
  return v;
}

// ======================= prep: all weight transposes + bias concat ==========
struct PrepArgs {
  const float* wsrc[12];
  u16* wdst[12];
  int K[12], N[12], toff[12];
  int ntile;
  const float* bsrc[6];
  float* qbE; float* qbD;
};

__global__ __launch_bounds__(256) void prep_kernel(PrepArgs a) {
  __shared__ float t[64][65];
  int bid = blockIdx.x, tid = threadIdx.x;
  if (bid < a.ntile) {
    int wi = 0;
#pragma unroll
    for (int i = 1; i < 12; ++i) if (bid >= a.toff[i]) wi = i;
    int tile = bid - a.toff[wi];
    int K = a.K[wi], N = a.N[wi];
    int ktiles = K >> 6;
    int k0 = (tile % ktiles) << 6, n0 = (tile / ktiles) << 6;
    const float* src = a.wsrc[wi];
    u16* dst = a.wdst[wi];
    int r = tid >> 4, c = (tid & 15) * 4;
#pragma unroll
    for (int i = 0; i < 4; ++i) {
      float4 v = *(const float4*)(src + (size_t)(k0 + r + i * 16) * N + n0 + c);
      t[r + i * 16][c + 0] = v.x; t[r + i * 16][c + 1] = v.y;
      t[r + i * 16][c + 2] = v.z; t[r + i * 16][c + 3] = v.w;
    }
    __syncthreads();
#pragma unroll
    for (int i = 0; i < 4; ++i) {
      int n = r + i * 16;
      ushort4 o;
      o.x = f2b(t[c + 0][n]); o.y = f2b(t[c + 1][n]);
      o.z = f2b(t[c + 2][n]); o.w = f2b(t[c + 3][n]);
      *(ushort4*)(dst + (size_t)(n0 + n) * K + k0 + c) = o;
    }
  } else {
    int j = (bid - a.ntile) * 256 + tid;   // 0..3071
    if (j < 3072) {
      int which = j >> 9, o = j & 511;
      float v = a.bsrc[which][o];
      if (which < 3) a.qbE[which * 512 + o] = v;
      else           a.qbD[(which - 3) * 512 + o] = v;
    }
  }
}

// ======================= embedding (both stacks in one launch) ==============
__global__ __launch_bounds__(256) void embed_kernel(const int* __restrict__ tokA,
                                                    const int* __restrict__ tokB,
                                                    const float* __restrict__ sw,
                                                    u16* __restrict__ bufA,
                                                    u16* __restrict__ bufB) {
  const int half = MP * DM / 256;
  int bid = blockIdx.x;
  const int* tok = (bid < half) ? tokA : tokB;
  u16* out = (bid < half) ? bufA : bufB;
  int idx = (bid < half ? bid : bid - half) * 256 + threadIdx.x;
  int row = idx >> 9, d = idx & 511;
  float v = 0.f;
  if (row < TQ) {
    int l = row % LSEQ;
    int t = tok[row];
    float freq = expf(-(float)(d >> 1) * (9.210340371976184f / 512.0f));
    float ang = (float)l * freq;
    float pe = (d & 1) ? cosf(ang) : sinf(ang);
    v = sw[(size_t)t * DM + d] + pe;
  }
  out[idx] = f2b(v);
}

// ======================= generic bf16 MFMA GEMM, 64x64 tile, BK=64 ==========
// A bf16 [MP][K]; BT bf16 [N][K]; bias f32; res/C bf16 [MP][ldc].
// LDS layout: tile[64 rows][128B], byte ^= (row&7)<<4 (conflict-free b128).
template<bool RELU, bool RES>
__global__ __launch_bounds__(256) void bgemm_kernel(
    const u16* __restrict__ A, const u16* __restrict__ BT,
    const float* __restrict__ bias, const u16* __restrict__ res,
    u16* __restrict__ C, int K, int ldc)
{
  __shared__ u16 As[64 * 64];
  __shared__ u16 Bs[64 * 64];
  const int tid = threadIdx.x;
  const int m0 = blockIdx.y << 6, n0 = blockIdx.x << 6;
  const int w = tid >> 6, lane = tid & 63;
  const int c = lane & 15, q = lane >> 4;
  const int srow = tid >> 2, sc = tid & 3;
  const int xr = (srow & 7) << 4;
  const u16* ag = A + (size_t)(m0 + srow) * K + sc * 16;
  const u16* bg = BT + (size_t)(n0 + srow) * K + sc * 16;
  const int arow = w * 16 + c;
  const int axr = (arow & 7) << 4;
  f32x4 acc[4];
#pragma unroll
  for (int t = 0; t < 4; ++t) acc[t] = (f32x4){0.f, 0.f, 0.f, 0.f};

  for (int k0 = 0; k0 < K; k0 += 64) {
    __syncthreads();
    uint4 a0 = *(const uint4*)(ag + k0);
    uint4 a1 = *(const uint4*)(ag + k0 + 8);
    uint4 b0 = *(const uint4*)(bg + k0);
    uint4 b1 = *(const uint4*)(bg + k0 + 8);
    *(uint4*)((char*)As + srow * 128 + ((sc * 32) ^ xr)) = a0;
    *(uint4*)((char*)As + srow * 128 + ((sc * 32 + 16) ^ xr)) = a1;
    *(uint4*)((char*)Bs + srow * 128 + ((sc * 32) ^ xr)) = b0;
    *(uint4*)((char*)Bs + srow * 128 + ((sc * 32 + 16) ^ xr)) = b1;
    __syncthreads();
#pragma unroll
    for (int ks = 0; ks < 2; ++ks) {
      bf16x8 af = *(bf16x8*)((char*)As + arow * 128 + ((ks * 64 + q * 16) ^ axr));
#pragma unroll
      for (int t = 0; t < 4; ++t) {
        int brow = t * 16 + c;
        bf16x8 bf = *(bf16x8*)((char*)Bs + brow * 128 + ((ks * 64 + q * 16) ^ ((brow & 7) << 4)));
        acc[t] = __builtin_amdgcn_mfma_f32_16x16x32_bf16(af, bf, acc[t], 0, 0, 0);
      }
    }
  }
  const int r0 = q * 4;
#pragma unroll
  for (int t = 0; t < 4; ++t) {
    int col = n0 + t * 16 + c;
    float bsv = bias[col];
#pragma unroll
    for (int r = 0; r < 4; ++r) {
      int row = m0 + w * 16 + r0 + r;
      float v = acc[t][r] + bsv;
      if (RES) v += b2f(res[(size_t)row * ldc + col]);
      if (RELU) v = fmaxf(v, 0.f);
      C[(size_t)row * ldc + col] = f2b(v);
    }
  }
}

// ======================= LayerNorm (4 rows per block) =======================
__global__ __launch_bounds__(256) void ln_kernel(u16* __restrict__ X,
                                                 const float* __restrict__ g,
                                                 const float* __restrict__ b) {
  int row = blockIdx.x * 4 + (threadIdx.x >> 6);
  int lane = threadIdx.x & 63;
  u16* p = X + (size_t)row * DM + lane * 8;
  uint4 u = *(uint4*)p;
  unsigned uu[4] = {u.x, u.y, u.z, u.w};
  float x[8];
#pragma unroll
  for (int e = 0; e < 4; ++e) {
    x[e * 2]     = b2f((u16)(uu[e] & 0xffff));
    x[e * 2 + 1] = b2f((u16)(uu[e] >> 16));
  }
  float s = 0.f;
#pragma unroll
  for (int j = 0; j < 8; ++j) s += x[j];
  s = wredsum(s);
  float mean = s * (1.0f / 512.0f);
  float d2 = 0.f;
#pragma unroll
  for (int j = 0; j < 8; ++j) { float d = x[j] - mean; d2 += d * d; }
  d2 = wredsum(d2);
  float r = rsqrtf(d2 * (1.0f / 512.0f) + 1e-5f);
  const float* gg = g + lane * 8;
  const float* bb = b + lane * 8;
  float y[8];
#pragma unroll
  for (int j = 0; j < 8; ++j) y[j] = (x[j] - mean) * r * gg[j] + bb[j];
  uint4 o;
  o.x = pk2(y[0], y[1]); o.y = pk2(y[2], y[3]);
  o.z = pk2(y[4], y[5]); o.w = pk2(y[6], y[7]);
  *(uint4*)p = o;
}

// ======================= MFMA attention, one (b,h) per block ================
// QKV bf16 [MP][1536]: q at h*64, k at 512+h*64, v at 1024+h*64.
// O bf16 [MP][512] written at col d*8+h (rearrange 'm n l d -> m l (d n)').
__global__ __launch_bounds__(256) void attn_kernel(
    const u16* __restrict__ QKV, const int* __restrict__ tok,
    u16* __restrict__ O, int causal)
{
  __shared__ u16 Qs[112 * 64];    // row stride 128B, byte ^= (r&7)<<4
  __shared__ u16 Ks[112 * 64];
  __shared__ u16 Vt[64 * 128];    // [d][k] row stride 256B, same XOR
  __shared__ u16 Ps[112 * 128];   // [m][k] row stride 256B, same XOR
  __shared__ int tokv[112];
  int b = blockIdx.x >> 3, h = blockIdx.x & 7;
  int tid = threadIdx.x;

  for (int i = tid; i < 4096; i += 256) ((u32*)Vt)[i] = 0;
  for (int i = tid; i < 7168; i += 256) ((u32*)Ps)[i] = 0;
  if (tid < 112) tokv[tid] = (tid < 100) ? (tok[b * LSEQ + tid] != 0) : 0;
  __syncthreads();

  const size_t rowbase = (size_t)(b * LSEQ) * 1536 + h * 64;
  for (int i = tid; i < 896; i += 256) {
    int r = i >> 3, c8 = i & 7;
    size_t g = rowbase + (size_t)r * 1536 + c8 * 8;
    uint4 q4 = *(const uint4*)(QKV + g);
    uint4 k4 = *(const uint4*)(QKV + g + 512);
    int off = (c8 * 16) ^ ((r & 7) << 4);
    *(uint4*)((char*)Qs + r * 128 + off) = q4;
    *(uint4*)((char*)Ks + r * 128 + off) = k4;
    if (r < LSEQ) {
      union { uint4 u; u16 s[8]; } cv;
      cv.u = *(const uint4*)(QKV + g + 1024);
#pragma unroll
      for (int j = 0; j < 8; ++j) {
        int d = c8 * 8 + j;
        *(u16*)((char*)Vt + d * 256 + ((2 * r) ^ ((d & 7) << 4))) = cv.s[j];
      }
    }
  }
  __syncthreads();

  const int lane = tid & 63, w = tid >> 6;
  const int c = lane & 15, q = lane >> 4;

#pragma unroll
  for (int half = 0; half < 2; ++half) {
    int mt = w + half * 4;
    if (mt > 6) continue;
    // ---- S = Q K^T (scaled+masked later) ----
    f32x4 s[7];
#pragma unroll
    for (int nt = 0; nt < 7; ++nt) s[nt] = (f32x4){0.f, 0.f, 0.f, 0.f};
    int arow = mt * 16 + c;
    int axr = (arow & 7) << 4;
    bf16x8 a0 = *(bf16x8*)((char*)Qs + arow * 128 + ((q * 16) ^ axr));
    bf16x8 a1 = *(bf16x8*)((char*)Qs + arow * 128 + ((64 + q * 16) ^ axr));
#pragma unroll
    for (int nt = 0; nt < 7; ++nt) {
      int brow = nt * 16 + c;
      int bxr = (brow & 7) << 4;
      bf16x8 b0 = *(bf16x8*)((char*)Ks + brow * 128 + ((q * 16) ^ bxr));
      bf16x8 b1 = *(bf16x8*)((char*)Ks + brow * 128 + ((64 + q * 16) ^ bxr));
      s[nt] = __builtin_amdgcn_mfma_f32_16x16x32_bf16(a0, b0, s[nt], 0, 0, 0);
      s[nt] = __builtin_amdgcn_mfma_f32_16x16x32_bf16(a1, b1, s[nt], 0, 0, 0);
    }
    // ---- softmax per row (rows q*4+r of this m-tile) -> P bf16 in LDS ----
#pragma unroll
    for (int r = 0; r < 4; ++r) {
      int mrow = mt * 16 + q * 4 + r;
      float sv[7];
      float mx = -3.0e38f;
#pragma unroll
      for (int nt = 0; nt < 7; ++nt) {
        int kcol = nt * 16 + c;
        float x = s[nt][r];
        bool real = kcol < LSEQ;
        bool ok = real && tokv[kcol] && (!causal || kcol <= mrow);
        x = ok ? x * 0.125f : (real ? -1e9f : -3.0e38f);
        sv[nt] = x;
        mx = fmaxf(mx, x);
      }
#pragma unroll
      for (int o = 1; o < 16; o <<= 1) mx = fmaxf(mx, __shfl_xor(mx, o, 64));
      float sum = 0.f;
#pragma unroll
      for (int nt = 0; nt < 7; ++nt) { sv[nt] = __expf(sv[nt] - mx); sum += sv[nt]; }
#pragma unroll
      for (int o = 1; o < 16; o <<= 1) sum += __shfl_xor(sum, o, 64);
      float inv = 1.0f / sum;
      int pxr = (mrow & 7) << 4;
#pragma unroll
      for (int nt = 0; nt < 7; ++nt) {
        int kcol = nt * 16 + c;
        *(u16*)((char*)Ps + mrow * 256 + ((2 * kcol) ^ pxr)) = f2b(sv[nt] * inv);
      }
    }
    // wave-local write->read ordering (cross-lane within the wave)
    asm volatile("s_waitcnt lgkmcnt(0)" ::: "memory");
    __builtin_amdgcn_sched_barrier(0);
    // ---- O = P @ V ----
    int prow = mt * 16 + c;
    int pxr2 = (prow & 7) << 4;
    bf16x8 pa[4];
#pragma unroll
    for (int ks = 0; ks < 4; ++ks)
      pa[ks] = *(bf16x8*)((char*)Ps + prow * 256 + ((ks * 64 + q * 16) ^ pxr2));
#pragma unroll
    for (int dt = 0; dt < 4; ++dt) {
      f32x4 o = (f32x4){0.f, 0.f, 0.f, 0.f};
      int vrow = dt * 16 + c;
      int vxr = (vrow & 7) << 4;
#pragma unroll
      for (int ks = 0; ks < 4; ++ks) {
        bf16x8 vb = *(bf16x8*)((char*)Vt + vrow * 256 + ((ks * 64 + q * 16) ^ vxr));
        o = __builtin_amdgcn_mfma_f32_16x16x32_bf16(pa[ks], vb, o, 0, 0, 0);
      }
#pragma unroll
      for (int r = 0; r < 4; ++r) {
        int mrow = mt * 16 + q * 4 + r;
        if (mrow < LSEQ) {
          int d = dt * 16 + c;
          O[(size_t)(b * LSEQ + mrow) * DM + d * 8 + h] = f2b(o[r]);
        }
      }
    }
  }
}

// ======================= vocab GEMM + fused softmax partials ================
// out[1600][32000] = (A bf16 [MP][512] * SCALEV) @ sw^T + fcb
// One block per 64-col stripe, sw stripe resident in LDS (fetched once).
template<bool PART>
__global__ __launch_bounds__(256) void vgemm_kernel(
    const u16* __restrict__ A, const float* __restrict__ sw,
    const float* __restrict__ fcb, float* __restrict__ out,
    float2* __restrict__ pbuf)
{
  __shared__ u16 Bs[64 * 512];   // 64 KB, row stride 1024B, byte ^= (row&7)<<4
  const int tid = threadIdx.x;
  const int n0 = blockIdx.x << 6;
  for (int i = tid; i < 4096; i += 256) {
    int row = i >> 6, c8 = i & 63;
    const float* s = sw + (size_t)(n0 + row) * DM + c8 * 8;
    float4 f0 = *(const float4*)s;
    float4 f1 = *(const float4*)(s + 4);
    uint4 o;
    o.x = pk2(f0.x, f0.y); o.y = pk2(f0.z, f0.w);
    o.z = pk2(f1.x, f1.y); o.w = pk2(f1.z, f1.w);
    *(uint4*)((char*)Bs + row * 1024 + ((c8 * 16) ^ ((row & 7) << 4))) = o;
  }
  __syncthreads();
  const int w = tid >> 6, lane = tid & 63;
  const int c = lane & 15, q = lane >> 4;
  const u16* pA = A + (size_t)(w * 16 + c) * DM + q * 8;
  float fb[4];
#pragma unroll
  for (int t = 0; t < 4; ++t) fb[t] = fcb[n0 + t * 16 + c];
  for (int mt = 0; mt < 25; ++mt) {
    f32x4 acc[4];
#pragma unroll
    for (int t = 0; t < 4; ++t) acc[t] = (f32x4){0.f, 0.f, 0.f, 0.f};
    size_t moff = (size_t)mt * 64 * DM;
#pragma unroll 4
    for (int ks = 0; ks < 16; ++ks) {
      union { uint4 u; bf16x8 b; } ca;
      ca.u = *(const uint4*)(pA + moff + ks * 32);
#pragma unroll
      for (int t = 0; t < 4; ++t) {
        int brow = t * 16 + c;
        bf16x8 bf = *(bf16x8*)((char*)Bs + brow * 1024 + ((ks * 64 + q * 16) ^ ((brow & 7) << 4)));
        acc[t] = __builtin_amdgcn_mfma_f32_16x16x32_bf16(ca.b, bf, acc[t], 0, 0, 0);
      }
    }
    float lv[4][4];
#pragma unroll
    for (int t = 0; t < 4; ++t)
#pragma unroll
      for (int r = 0; r < 4; ++r) lv[t][r] = acc[t][r] * SCALEV + fb[t];
#pragma unroll
    for (int t = 0; t < 4; ++t) {
      int col = n0 + t * 16 + c;
#pragma unroll
      for (int r = 0; r < 4; ++r) {
        int row = mt * 64 + w * 16 + q * 4 + r;
        out[(size_t)row * VOCAB + col] = lv[t][r];
      }
    }
    if (PART) {
      float pm[4], ps[4];
#pragma unroll
      for (int r = 0; r < 4; ++r) {
        float mx = fmaxf(fmaxf(lv[0][r], lv[1][r]), fmaxf(lv[2][r], lv[3][r]));
#pragma unroll
        for (int o = 1; o < 16; o <<= 1) mx = fmaxf(mx, __shfl_xor(mx, o, 64));
        float ss = 0.f;
#pragma unroll
        for (int t = 0; t < 4; ++t) ss += __expf(lv[t][r] - mx);
#pragma unroll
        for (int o = 1; o < 16; o <<= 1) ss += __shfl_xor(ss, o, 64);
        pm[r] = mx; ps[r] = ss;
      }
      if (c < 4) {
        int row = mt * 64 + w * 16 + q * 4 + c;
        pbuf[(size_t)row * NSTRIPE + blockIdx.x] = make_float2(pm[c], ps[c]);
      }
    }
  }
}

// ======================= softmax finalize ===================================
__global__ __launch_bounds__(256) void reduce_partials(const float2* __restrict__ pbuf,
                                                       float2* __restrict__ MS) {
  int row = blockIdx.x * 4 + (threadIdx.x >> 6);
  int lane = threadIdx.x & 63;
  float m = -3.0e38f, s = 0.f;
  for (int i = lane; i < NSTRIPE; i += 64) {
    float2 p = pbuf[(size_t)row * NSTRIPE + i];
    float mn = fmaxf(m, p.x);
    s = s * __expf(m - mn) + p.y * __expf(p.x - mn);
    m = mn;
  }
#pragma unroll
  for (int o = 1; o < 64; o <<= 1) {
    float m2 = __shfl_xor(m, o, 64);
    float s2 = __shfl_xor(s, o, 64);
    float mn = fmaxf(m, m2);
    s = s * __expf(m - mn) + s2 * __expf(m2 - mn);
    m = mn;
  }
  if (lane == 0) MS[row] = make_float2(m, 1.0f / s);
}

__global__ __launch_bounds__(256) void rowstat_kernel(const float* __restrict__ L,
                                                      float2* __restrict__ MS) {
  __shared__ float am[4], as_[4];
  int row = blockIdx.x, tid = threadIdx.x;
  const float* p = L + (size_t)row * VOCAB;
  float m = -3.0e38f, s = 0.f;
  for (int i = tid; i < VOCAB; i += 256) {
    float x = p[i];
    if (x > m) { s *= __expf(m - x); m = x; }
    s += __expf(x - m);
  }
#pragma unroll
  for (int o = 1; o < 64; o <<= 1) {
    float m2 = __shfl_xor(m, o, 64);
    float s2 = __shfl_xor(s, o, 64);
    float mn = fmaxf(m, m2);
    s = s * __expf(m - mn) + s2 * __expf(m2 - mn);
    m = mn;
  }
  if ((tid & 63) == 0) { am[tid >> 6] = m; as_[tid >> 6] = s; }
  __syncthreads();
  if (tid == 0) {
    float M = am[0], S = as_[0];
#pragma unroll
    for (int k = 1; k < 4; ++k) {
      float mn = fmaxf(M, am[k]);
      S = S * __expf(M - mn) + as_[k] * __expf(am[k] - mn);
      M = mn;
    }
    MS[row] = make_float2(M, 1.0f / S);
  }
}

__global__ __launch_bounds__(256) void vfinal_kernel(float* __restrict__ P,
                                                     const float2* __restrict__ MS) {
  int row = blockIdx.y;
  int col = blockIdx.x * 1024 + threadIdx.x * 4;
  if (col >= VOCAB) return;
  float2 ms = MS[row];
  float* p = P + (size_t)row * VOCAB + col;
  float4 x = *(float4*)p;
  x.x = __expf(x.x - ms.x) * ms.y;
  x.y = __expf(x.y - ms.x) * ms.y;
  x.z = __expf(x.z - ms.x) * ms.y;
  x.w = __expf(x.w - ms.x) * ms.y;
  *(float4*)p = x;
}

// ======================= host ===============================================
extern "C" void kernel_launch(void* const* d_in, const int* in_sizes, int n_in,
                              void* d_out, int out_size, void* d_ws, size_t ws_size,
                              hipStream_t stream) {
  (void)in_sizes; (void)n_in; (void)out_size;
  const int* inputs  = (const int*)d_in[0];
  const int* outputs = (const int*)d_in[1];
  const float* sw  = (const float*)d_in[2];
  const float* fcb = (const float*)d_in[3];
  const float* E[16];
  const float* Dd[16];
  for (int i = 0; i < 16; ++i) E[i]  = (const float*)d_in[4 + i];
  for (int i = 0; i < 16; ++i) Dd[i] = (const float*)d_in[20 + i];

  // ws: bufE, bufD (bf16), MS (1600 float2), pbuf (1600*500 float2)
  u16* bufE = (u16*)d_ws;
  u16* bufD = bufE + (size_t)MP * DM;
  size_t offMS = (size_t)2 * MP * DM * 2;
  size_t offPB = offMS + (size_t)TQ * 8;
  size_t need  = offPB + (size_t)TQ * NSTRIPE * 8;
  float2* MS   = (float2*)((char*)d_ws + offMS);
  float2* pbuf = (float2*)((char*)d_ws + offPB);
  bool part = ws_size >= need;

  // transient carve from d_out (dead before vgemm writes logits)
  char* base = (char*)d_out;
  size_t off = 0;
  auto carve = [&](size_t bytes) { void* p = base + off; off += (bytes + 255) & ~(size_t)255; return p; };
  u16* bqkvE = (u16*)carve((size_t)MP * 1536 * 2);
  u16* bqkvD = (u16*)carve((size_t)MP * 1536 * 2);
  u16* ba    = (u16*)carve((size_t)MP * DM * 2);
  u16* bh    = (u16*)carve((size_t)MP * HID * 2);
  u16* wqkvE = (u16*)carve((size_t)1536 * 512 * 2);
  u16* woE   = (u16*)carve((size_t)512 * 512 * 2);
  u16* f1E   = (u16*)carve((size_t)2048 * 512 * 2);
  u16* f2E   = (u16*)carve((size_t)512 * 2048 * 2);
  u16* wqkvD = (u16*)carve((size_t)1536 * 512 * 2);
  u16* woD   = (u16*)carve((size_t)512 * 512 * 2);
  u16* f1D   = (u16*)carve((size_t)2048 * 512 * 2);
  u16* f2D   = (u16*)carve((size_t)512 * 2048 * 2);
  float* qbE = (float*)carve(1536 * 4);
  float* qbD = (float*)carve(1536 * 4);
  float* out = (float*)d_out;

  // ---- prep (all weight transposes + bias concats) ----
  PrepArgs pa;
  const float* ws_[12] = {E[0], E[2], E[4], E[6], E[10], E[12],
                          Dd[0], Dd[2], Dd[4], Dd[6], Dd[10], Dd[12]};
  u16* wd_[12] = {wqkvE, wqkvE + 512 * 512, wqkvE + 1024 * 512, woE, f1E, f2E,
                  wqkvD, wqkvD + 512 * 512, wqkvD + 1024 * 512, woD, f1D, f2D};
  int K_[12] = {512, 512, 512, 512, 512, 2048, 512, 512, 512, 512, 512, 2048};
  int N_[12] = {512, 512, 512, 512, 2048, 512, 512, 512, 512, 512, 2048, 512};
  int tiles = 0;
  for (int i = 0; i < 12; ++i) {
    pa.wsrc[i] = ws_[i]; pa.wdst[i] = wd_[i]; pa.K[i] = K_[i]; pa.N[i] = N_[i];
    pa.toff[i] = tiles;
    tiles += (K_[i] >> 6) * (N_[i] >> 6);
  }
  pa.ntile = tiles;                  // 1536
  const float* bs_[6] = {E[1], E[3], E[5], Dd[1], Dd[3], Dd[5]};
  for (int i = 0; i < 6; ++i) pa.bsrc[i] = bs_[i];
  pa.qbE = qbE; pa.qbD = qbD;
  prep_kernel<<<tiles + 12, 256, 0, stream>>>(pa);

  embed_kernel<<<2 * MP * DM / 256, 256, 0, stream>>>(inputs, outputs, sw, bufE, bufD);

  const dim3 Gqkv(24, 26), G512(8, 26), Gkv(16, 26), Ghid(32, 26);

  for (int it = 0; it < 2; ++it) {
    bgemm_kernel<false,false><<<Gqkv,256,0,stream>>>(bufE, wqkvE, qbE, nullptr, bqkvE, 512, 1536);
    attn_kernel<<<128,256,0,stream>>>(bqkvE, inputs, ba, 0);
    bgemm_kernel<false,true><<<G512,256,0,stream>>>(ba, woE, E[7], bufE, bufE, 512, 512);
    ln_kernel<<<TQ/4,256,0,stream>>>(bufE, E[8], E[9]);
    bgemm_kernel<true,false><<<Ghid,256,0,stream>>>(bufE, f1E, E[11], nullptr, bh, 512, 2048);
    bgemm_kernel<false,true><<<G512,256,0,stream>>>(bh, f2E, E[13], bufE, bufE, 2048, 512);
    ln_kernel<<<TQ/4,256,0,stream>>>(bufE, E[14], E[15]);
  }
  for (int it = 0; it < 2; ++it) {
    bgemm_kernel<false,false><<<Gqkv,256,0,stream>>>(bufD, wqkvD, qbD, nullptr, bqkvD, 512, 1536);
    attn_kernel<<<128,256,0,stream>>>(bqkvD, outputs, ba, 1);
    bgemm_kernel<false,true><<<G512,256,0,stream>>>(ba, woD, Dd[7], bufD, bufD, 512, 512);
    ln_kernel<<<TQ/4,256,0,stream>>>(bufD, Dd[8], Dd[9]);
    bgemm_kernel<false,false><<<G512,256,0,stream>>>(bufD, wqkvD, qbD, nullptr, bqkvD, 512, 1536);
    bgemm_kernel<false,false><<<Gkv,256,0,stream>>>(bufE, wqkvD + 512 * 512, qbD + 512, nullptr, bqkvD + 512, 512, 1536);
    attn_kernel<<<128,256,0,stream>>>(bqkvD, inputs, ba, 0);
    bgemm_kernel<false,true><<<G512,256,0,stream>>>(ba, woD, Dd[7], bufD, bufD, 512, 512);
    ln_kernel<<<TQ/4,256,0,stream>>>(bufD, Dd[8], Dd[9]);
    bgemm_kernel<true,false><<<Ghid,256,0,stream>>>(bufD, f1D, Dd[11], nullptr, bh, 512, 2048);
    bgemm_kernel<false,true><<<G512,256,0,stream>>>(bh, f2D, Dd[13], bufD, bufD, 2048, 512);
    ln_kernel<<<TQ/4,256,0,stream>>>(bufD, Dd[14], Dd[15]);
  }

  if (part) {
    vgemm_kernel<true><<<NSTRIPE, 256, 0, stream>>>(bufD, sw, fcb, out, pbuf);
    reduce_partials<<<TQ / 4, 256, 0, stream>>>(pbuf, MS);
  } else {
    vgemm_kernel<false><<<NSTRIPE, 256, 0, stream>>>(bufD, sw, fcb, out, nullptr);
    rowstat_kernel<<<TQ, 256, 0, stream>>>(out, MS);
  }
  vfinal_kernel<<<dim3(32, TQ), 256, 0, stream>>>(out, MS);
}